// Round 4
// baseline (131028.052 us; speedup 1.0000x reference)
//
#include <hip/hip_runtime.h>
#include <math.h>

#define B_ 16
#define S_ 512
#define FRAME_ 438
#define DM_ 800
#define H_ 8
#define DH_ 100
#define FFN_ 1024
#define HID_ 1024
#define POSE_ 274
#define WIN_ 100
#define G4_ 4096     // 4*HID
#define NBLK_ 512    // persistent decoder grid (2 blocks/CU on 256 CUs)

// ---------------------------------------------------------------------------
// gemm128: fp32, 128x128 tile, 256 thr, 8x8 micro (split 4+4, conflict-free
// LDS). C = A@B (+bias[N]) (+res[M,N]) (+pos_table[posidx[m]]) (relu).
// ---------------------------------------------------------------------------
__global__ __launch_bounds__(256) void gemm128(
    const float* __restrict__ A, const float* __restrict__ Bm,
    float* __restrict__ C, int M, int N, int K,
    const float* __restrict__ bias, const float* __restrict__ res,
    const int* __restrict__ posidx, const float* __restrict__ postab,
    int relu)
{
    __shared__ float As[16 * 132];
    __shared__ float Bs[16 * 132];
    int m0 = blockIdx.x * 128, n0 = blockIdx.y * 128;
    int tid = threadIdx.x;
    int tx = tid & 15, ty = tid >> 4;
    float acc[8][8];
#pragma unroll
    for (int i = 0; i < 8; ++i)
#pragma unroll
        for (int j = 0; j < 8; ++j) acc[i][j] = 0.f;

    for (int k0 = 0; k0 < K; k0 += 16) {
#pragma unroll
        for (int i = 0; i < 8; ++i) {             // A: 128 m x 16 k
            int idx = i * 256 + tid;
            int m = idx >> 4, kl = idx & 15;
            int r = m0 + m, k = k0 + kl;
            As[kl * 132 + m] = (r < M && k < K) ? A[(long)r * K + k] : 0.f;
        }
#pragma unroll
        for (int i = 0; i < 8; ++i) {             // B: 16 k x 128 n
            int idx = i * 256 + tid;
            int n = idx & 127, k = idx >> 7;
            int kk = k0 + k, nn = n0 + n;
            Bs[k * 132 + n] = (kk < K && nn < N) ? Bm[(long)kk * N + nn] : 0.f;
        }
        __syncthreads();
#pragma unroll
        for (int kk = 0; kk < 16; ++kk) {
            float4 a0 = *(const float4*)&As[kk * 132 + ty * 4];
            float4 a1 = *(const float4*)&As[kk * 132 + 64 + ty * 4];
            float4 b0 = *(const float4*)&Bs[kk * 132 + tx * 4];
            float4 b1 = *(const float4*)&Bs[kk * 132 + 64 + tx * 4];
            float a[8] = {a0.x, a0.y, a0.z, a0.w, a1.x, a1.y, a1.z, a1.w};
            float b[8] = {b0.x, b0.y, b0.z, b0.w, b1.x, b1.y, b1.z, b1.w};
#pragma unroll
            for (int i = 0; i < 8; ++i)
#pragma unroll
                for (int j = 0; j < 8; ++j) acc[i][j] += a[i] * b[j];
        }
        __syncthreads();
    }
#pragma unroll
    for (int i = 0; i < 8; ++i) {
        int m = m0 + ((i < 4) ? (ty * 4 + i) : (64 + ty * 4 + i - 4));
        if (m >= M) continue;
#pragma unroll
        for (int j = 0; j < 8; ++j) {
            int n = n0 + ((j < 4) ? (tx * 4 + j) : (64 + tx * 4 + j - 4));
            if (n >= N) continue;
            float v = acc[i][j];
            if (bias) v += bias[n];
            if (res) v += res[(long)m * N + n];
            if (posidx) v += postab[(long)posidx[m] * N + n];
            if (relu) v = fmaxf(v, 0.f);
            C[(long)m * N + n] = v;
        }
    }
}

// ---------------------------------------------------------------------------
// LayerNorm over last dim N (=800), one block per row.
// ---------------------------------------------------------------------------
__global__ __launch_bounds__(256) void ln_f32(
    const float* __restrict__ X, float* __restrict__ Y,
    const float* __restrict__ g, const float* __restrict__ b, int N)
{
    int m = blockIdx.x;
    const float* x = X + (long)m * N;
    __shared__ float red[256];
    int tid = threadIdx.x;
    float s = 0.f;
    for (int i = tid; i < N; i += 256) s += x[i];
    red[tid] = s; __syncthreads();
    for (int o = 128; o > 0; o >>= 1) { if (tid < o) red[tid] += red[tid + o]; __syncthreads(); }
    float mean = red[0] / N;
    __syncthreads();
    float v = 0.f;
    for (int i = tid; i < N; i += 256) { float d = x[i] - mean; v += d * d; }
    red[tid] = v; __syncthreads();
    for (int o = 128; o > 0; o >>= 1) { if (tid < o) red[tid] += red[tid + o]; __syncthreads(); }
    float rs = rsqrtf(red[0] / N + 1e-6f);
    for (int i = tid; i < N; i += 256)
        Y[(long)m * N + i] = (x[i] - mean) * rs * g[i] + b[i];
}

// ---------------------------------------------------------------------------
// Fused banded attention (verified round 1).
// ---------------------------------------------------------------------------
__global__ __launch_bounds__(256) void attn_f32(
    const float* __restrict__ Q, const float* __restrict__ K,
    const float* __restrict__ V, float* __restrict__ O)
{
    int blk = blockIdx.x;
    int qt = blk & 127; int bh = blk >> 7;
    int h = bh & 7; int b = bh >> 3;
    int q0 = qt * 4;
    int tid = threadIdx.x;

    __shared__ float qv[4][DH_];
    __shared__ float sc[4][208];
    __shared__ float red[256];
    __shared__ float inv_den[4];

    for (int i = tid; i < 4 * DH_; i += 256) {
        int qi = i / DH_, d = i - qi * DH_;
        qv[qi][d] = Q[(long)(b * S_ + q0 + qi) * DM_ + h * DH_ + d];
    }
    __syncthreads();

    int w = tid;
    int k = q0 - WIN_ + w;
    bool kvalid = (w < 204) && (k >= 0) && (k < S_);
    float dots[4] = {0.f, 0.f, 0.f, 0.f};
    if (kvalid) {
        const float* krow = K + (long)(b * S_ + k) * DM_ + h * DH_;
        for (int d = 0; d < DH_; ++d) {
            float kvv = krow[d];
#pragma unroll
            for (int qi = 0; qi < 4; ++qi) dots[qi] += qv[qi][d] * kvv;
        }
    }
#pragma unroll
    for (int qi = 0; qi < 4; ++qi) {
        int wq = w - qi;
        if (w < 204 && wq >= 0 && wq < 201)
            sc[qi][wq] = kvalid ? dots[qi] * 0.1f : -1e30f;
    }
    __syncthreads();

    for (int qi = 0; qi < 4; ++qi) {
        float vmax = (tid < 201) ? sc[qi][tid] : -1e30f;
        red[tid] = vmax; __syncthreads();
        for (int o = 128; o > 0; o >>= 1) { if (tid < o) red[tid] = fmaxf(red[tid], red[tid + o]); __syncthreads(); }
        float mx = red[0];
        __syncthreads();
        float e = 0.f;
        if (tid < 201) { e = __expf(sc[qi][tid] - mx); sc[qi][tid] = e; }
        red[tid] = e; __syncthreads();
        for (int o = 128; o > 0; o >>= 1) { if (tid < o) red[tid] += red[tid + o]; __syncthreads(); }
        if (tid == 0) inv_den[qi] = 1.f / red[0];
        __syncthreads();
    }

    if (tid < DH_) {
        int d = tid;
        float o_[4] = {0.f, 0.f, 0.f, 0.f};
        for (int w2 = 0; w2 < 204; ++w2) {
            int k2 = q0 - WIN_ + w2;
            if (k2 < 0 || k2 >= S_) continue;
            float vv = V[(long)(b * S_ + k2) * DM_ + h * DH_ + d];
#pragma unroll
            for (int qi = 0; qi < 4; ++qi) {
                int wq = w2 - qi;
                if (wq >= 0 && wq < 201) o_[qi] += sc[qi][wq] * vv;
            }
        }
#pragma unroll
        for (int qi = 0; qi < 4; ++qi)
            O[(long)(b * S_ + q0 + qi) * DM_ + h * DH_ + d] = o_[qi] * inv_den[qi];
    }
}

// g3[j] = out_b @ Wx
__global__ __launch_bounds__(256) void g3_kernel(
    const float* __restrict__ outb, const float* __restrict__ Wx, float* __restrict__ g3)
{
    int j = blockIdx.x * 256 + threadIdx.x;
    if (j >= G4_) return;
    float s = 0.f;
    for (int p = 0; p < POSE_; ++p) s += outb[p] * Wx[(long)p * G4_ + j];
    g3[j] = s;
}

// ---------------------------------------------------------------------------
// tr_cat: WT[c][k] = (k<K1 ? in1[k][c] : k<K1+K2 ? in2[k-K1][c] : 0)
// in row-major with 4096 cols; WT row stride KP. grid (KP/64, 64).
// ---------------------------------------------------------------------------
__global__ __launch_bounds__(256) void tr_cat(
    const float* __restrict__ in1, const float* __restrict__ in2,
    float* __restrict__ WT, int K1, int K2, int KP)
{
    __shared__ float tile[64][65];
    int k0 = blockIdx.x * 64, c0 = blockIdx.y * 64;
    int tid = threadIdx.x;
    int cl = tid & 63, kr = tid >> 6;
#pragma unroll
    for (int i = 0; i < 16; ++i) {
        int kl = i * 4 + kr;
        int k = k0 + kl, c = c0 + cl;
        float v = 0.f;
        if (k < K1) v = in1[(long)k * G4_ + c];
        else if (k < K1 + K2) v = in2[(long)(k - K1) * G4_ + c];
        tile[kl][cl] = v;
    }
    __syncthreads();
    int kl2 = tid & 63, cr = tid >> 6;
#pragma unroll
    for (int i = 0; i < 16; ++i) {
        int ci = i * 4 + cr;
        WT[(long)(c0 + ci) * KP + k0 + kl2] = tile[kl2][ci];
    }
}

// dec_init: HP0 = vec_h; zero the grid-barrier counter.
__global__ __launch_bounds__(256) void dec_init(
    const float* __restrict__ vh, float* __restrict__ HP0, int* __restrict__ counter)
{
    int i = blockIdx.x * 256 + threadIdx.x;
    if (i < B_ * HID_) HP0[i] = vh[i];
    if (i == 0) *counter = 0;
}

// ---------------------------------------------------------------------------
// lstm_persist: ONE kernel runs all 512 steps. 512 blocks x 256 thr,
// exactly 2 blocks/CU (64 KB LDS each). Block owns 8 gate-cols (2 hids x 4
// gates). Per step: h (prev) staged to LDS [b][k] with float4-XOR swizzle
// (conflict-free b128 reads, 8-way broadcast); weight slice (32 KB, L1/L2-
// hot) streamed as float4; x-part dotted from L2-hot tgt/enc rows. c-state
// in owner registers. Grid barrier: device-scope atomic counter, monotone
// target, one barrier/step (h ping-pong removes the second).
// ---------------------------------------------------------------------------
__global__ __launch_bounds__(256, 2) void lstm_persist(
    const float* __restrict__ WhT, const float* __restrict__ WEFFT,
    const float* __restrict__ Wx, const float* __restrict__ G2,
    const float* __restrict__ g3, const float* __restrict__ lstm_b,
    const int* __restrict__ epoch,
    const float* __restrict__ tgt, const float* __restrict__ dec0,
    const float* __restrict__ ENC, const float* __restrict__ vec_c,
    float* __restrict__ HPa, float* __restrict__ HPb,
    float* __restrict__ Hall, int* __restrict__ counter)
{
    __shared__ float lds[16384];   // [0,16384): h ; reused: partials + gates
    const int tid = threadIdx.x, blk = blockIdx.x;
    const int c = tid & 7, kgr = tid >> 3;          // col-idx, k-group
    const int gate = c >> 1, e = c & 1;
    const int col = gate * HID_ + blk * 2 + e;
    const int p = (int)((double)epoch[0] * 0.01);   // match int(epoch*LAMB)
    const int per = p + 10;

    // owner-thread persistent cell state
    const int ob3 = tid >> 1, oe = tid & 1, ohid = blk * 2 + oe;
    float creg = (tid < 32) ? vec_c[ob3 * HID_ + ohid] : 0.f;

    const float4* wA = (const float4*)(WhT   + (long)col * HID_ + kgr * 32);
    const float4* wB = (const float4*)(WEFFT + (long)col * HID_ + kgr * 32);

    for (int t = 0; t < S_; ++t) {
        const bool msk = (t % per) >= p;
        const bool useA = msk || (t == 0);
        const float* HIN = (t & 1) ? HPb : HPa;

        // ---- stage h -> lds[b][k], float4-granular swizzle (j4+kd)&7 ----
        {
            const float4* h4 = (const float4*)HIN;
#pragma unroll
            for (int i = 0; i < 16; ++i) {
                int idx = i * 256 + tid;
                int b = idx >> 8, q = idx & 255;
                int kd = q >> 3, j4 = q & 7;
                float4 v = h4[idx];
                *(float4*)&lds[b * 1024 + kd * 32 + ((j4 + kd) & 7) * 4] = v;
            }
        }
        __syncthreads();

        // ---- h-part dots: acc[b] += Wsel[k,col]*h[b,k], k in kgr*32.. ----
        float acc[16];
#pragma unroll
        for (int b = 0; b < 16; ++b) acc[b] = 0.f;
        {
            const float4* wr = useA ? wA : wB;
            float4 w[8];
#pragma unroll
            for (int j4 = 0; j4 < 8; ++j4) w[j4] = wr[j4];
#pragma unroll
            for (int j4 = 0; j4 < 8; ++j4) {
                int js = ((j4 + kgr) & 7) * 4;
#pragma unroll
                for (int b = 0; b < 16; ++b) {
                    float4 h4 = *(const float4*)&lds[b * 1024 + kgr * 32 + js];
                    acc[b] += w[j4].x * h4.x + w[j4].y * h4.y
                            + w[j4].z * h4.z + w[j4].w * h4.w;
                }
            }
        }

        // ---- x-part dots (from global; rows are L2-hot) ----
        {
            int KX; const float* XW; const float* xbase; long xstr;
            if (useA) {
                KX = POSE_; XW = Wx;
                if (msk) { xbase = tgt + (long)t * POSE_; xstr = (long)S_ * POSE_; }
                else     { xbase = dec0;                  xstr = POSE_; }
            } else {
                KX = DM_; XW = G2;
                xbase = ENC + (long)(t - 1) * DM_; xstr = (long)S_ * DM_;
            }
            int kx0 = (KX * kgr) >> 5, kx1 = (KX * (kgr + 1)) >> 5;
#pragma unroll 2
            for (int kx = kx0; kx < kx1; ++kx) {
                float wv = XW[(long)kx * G4_ + col];
#pragma unroll
                for (int b = 0; b < 16; ++b)
                    acc[b] += wv * xbase[(long)b * xstr + kx];
            }
        }

        // ---- partials -> LDS (h region dead), reduce over 32 k-groups ----
        __syncthreads();
#pragma unroll
        for (int b = 0; b < 16; ++b)
            lds[(kgr * 8 + c) * 17 + b] = acc[b];
        __syncthreads();
        if (tid < 128) {
            int ob = tid >> 3, oc = tid & 7;
            float s = 0.f;
#pragma unroll
            for (int kg = 0; kg < 32; ++kg)
                s += lds[(kg * 8 + oc) * 17 + ob];
            int colr = (oc >> 1) * HID_ + blk * 2 + (oc & 1);
            s += lstm_b[colr];
            if (!useA) s += g3[colr];
            lds[8192 + oc * 16 + ob] = s;
        }
        __syncthreads();

        // ---- elementwise LSTM update (owner threads) ----
        if (tid < 32) {
            float iv = lds[8192 + (0 * 2 + oe) * 16 + ob3];
            float fv = lds[8192 + (1 * 2 + oe) * 16 + ob3];
            float gv = lds[8192 + (2 * 2 + oe) * 16 + ob3];
            float ov = lds[8192 + (3 * 2 + oe) * 16 + ob3];
            float ig = 1.f / (1.f + __expf(-iv));
            float fg = 1.f / (1.f + __expf(-fv));
            float og = 1.f / (1.f + __expf(-ov));
            float cn = fg * creg + ig * tanhf(gv);
            float hn = og * tanhf(cn);
            creg = cn;
            float* HOUT = (t & 1) ? HPa : HPb;
            HOUT[ob3 * HID_ + ohid] = hn;
            Hall[((long)ob3 * S_ + t) * HID_ + ohid] = hn;
        }

        // ---- grid barrier (release h writes, acquire before next stage) ----
        __syncthreads();
        if (tid == 0) {
            __threadfence();
            __hip_atomic_fetch_add(counter, 1, __ATOMIC_ACQ_REL,
                                   __HIP_MEMORY_SCOPE_AGENT);
            int target = (t + 1) * NBLK_;
            int guard = 0;
            while (__hip_atomic_load(counter, __ATOMIC_ACQUIRE,
                                     __HIP_MEMORY_SCOPE_AGENT) < target
                   && ++guard < (1 << 28))
                __builtin_amdgcn_s_sleep(2);
        }
        __syncthreads();
    }
}

// ---------------------------------------------------------------------------
extern "C" void kernel_launch(void* const* d_in, const int* in_sizes, int n_in,
                              void* d_out, int out_size, void* d_ws, size_t ws_size,
                              hipStream_t stream) {
    const float* src_seq  = (const float*)d_in[0];
    const int*   src_pos  = (const int*)  d_in[1];
    const float* tgt_seq  = (const float*)d_in[2];
    const float* vec_h    = (const float*)d_in[3];
    const float* vec_c    = (const float*)d_in[4];
    const float* dec0     = (const float*)d_in[5];
    const float* emb_W    = (const float*)d_in[6];
    const float* emb_b    = (const float*)d_in[7];
    const float* pos_tab  = (const float*)d_in[8];
    const float* Wq       = (const float*)d_in[9];
    const float* Wk       = (const float*)d_in[10];
    const float* Wv       = (const float*)d_in[11];
    const float* Wo       = (const float*)d_in[12];
    const float* ln1_g    = (const float*)d_in[13];
    const float* ln1_b    = (const float*)d_in[14];
    const float* ffn_W1   = (const float*)d_in[15];
    const float* ffn_b1   = (const float*)d_in[16];
    const float* ffn_W2   = (const float*)d_in[17];
    const float* ffn_b2   = (const float*)d_in[18];
    const float* ln2_g    = (const float*)d_in[19];
    const float* ln2_b    = (const float*)d_in[20];
    const float* lstm_Wx  = (const float*)d_in[21];
    const float* lstm_Wh  = (const float*)d_in[22];
    const float* lstm_b   = (const float*)d_in[23];
    const float* out_W    = (const float*)d_in[24];
    const float* out_b    = (const float*)d_in[25];
    const int*   epoch    = (const int*)  d_in[26];

    // ---- workspace layout (peak = round-3's proven ~165 MB footprint) ----
    float* ws = (float*)d_ws;
    const long NX = (long)B_ * S_ * DM_;           // 6,553,600
    float* X      = ws;                            // enc (live to the end)
    float* R      = X + NX;                        // 34,603,008-float region
    // encoder phase:
    float* Qb     = R;
    float* Kb     = Qb + NX;
    float* Vb     = Kb + NX;
    float* Ob     = Vb + NX;
    float* FFNH   = Ob + NX;
    // decoder phase (aliases into R):
    float* WEFF_t = R;                             // 4,194,304 (dead after tr_cat)
    float* WhT    = R + 4194304;                   // 4,194,304 (4096 x 1024)
    float* WEFFT  = R + 8388608;                   // 4,194,304 (4096 x 1024)
    float* G2     = R + 12582912;                  // 3,276,800 (800 x 4096)
    float* Hall   = R + 15859712;                  // 8,388,608 (B*S x 1024)
    float* T1     = R + 24248320;                  // 2,244,608 (B*S x 274)
    float* TAIL   = R + 34603008;
    float* G3v    = TAIL;                          // 4096
    float* HP0    = G3v + G4_;                     // 16384
    float* HP1    = HP0 + B_ * HID_;               // 16384
    int*   CNT    = (int*)(HP1 + B_ * HID_);

    const int M = B_ * S_; // 8192
    dim3 blk(256);

    // ---- encoder ----
    gemm128<<<dim3(M / 128, (DM_ + 127) / 128), blk, 0, stream>>>(
        src_seq, emb_W, X, M, DM_, FRAME_, emb_b, nullptr, src_pos, pos_tab, 0);
    gemm128<<<dim3(M / 128, (DM_ + 127) / 128), blk, 0, stream>>>(
        X, Wq, Qb, M, DM_, DM_, nullptr, nullptr, nullptr, nullptr, 0);
    gemm128<<<dim3(M / 128, (DM_ + 127) / 128), blk, 0, stream>>>(
        X, Wk, Kb, M, DM_, DM_, nullptr, nullptr, nullptr, nullptr, 0);
    gemm128<<<dim3(M / 128, (DM_ + 127) / 128), blk, 0, stream>>>(
        X, Wv, Vb, M, DM_, DM_, nullptr, nullptr, nullptr, nullptr, 0);
    attn_f32<<<dim3(B_ * H_ * (S_ / 4)), blk, 0, stream>>>(Qb, Kb, Vb, Ob);
    gemm128<<<dim3(M / 128, (DM_ + 127) / 128), blk, 0, stream>>>(
        Ob, Wo, FFNH, M, DM_, DM_, nullptr, X, nullptr, nullptr, 0);
    ln_f32<<<dim3(M), blk, 0, stream>>>(FFNH, X, ln1_g, ln1_b, DM_);
    gemm128<<<dim3(M / 128, FFN_ / 128), blk, 0, stream>>>(
        X, ffn_W1, FFNH, M, FFN_, DM_, ffn_b1, nullptr, nullptr, nullptr, 1);
    gemm128<<<dim3(M / 128, (DM_ + 127) / 128), blk, 0, stream>>>(
        FFNH, ffn_W2, Ob, M, DM_, FFN_, ffn_b2, X, nullptr, nullptr, 0);
    ln_f32<<<dim3(M), blk, 0, stream>>>(Ob, X, ln2_g, ln2_b, DM_);   // X = enc

    // ---- decoder precompute ----
    // WEFF_t = out_W[:1024]@lstm_Wx + lstm_Wh   (1024 x 4096)
    gemm128<<<dim3(HID_ / 128, G4_ / 128), blk, 0, stream>>>(
        out_W, lstm_Wx, WEFF_t, HID_, G4_, POSE_, nullptr, lstm_Wh,
        nullptr, nullptr, 0);
    // G2 = out_W[1024:]@lstm_Wx   (800 x 4096)
    gemm128<<<dim3((DM_ + 127) / 128, G4_ / 128), blk, 0, stream>>>(
        out_W + (long)HID_ * POSE_, lstm_Wx, G2, DM_, G4_, POSE_,
        nullptr, nullptr, nullptr, nullptr, 0);
    // transposed step weights (4096 x 1024 each)
    tr_cat<<<dim3(HID_ / 64, G4_ / 64), blk, 0, stream>>>(
        lstm_Wh, nullptr, WhT, HID_, 0, HID_);
    tr_cat<<<dim3(HID_ / 64, G4_ / 64), blk, 0, stream>>>(
        WEFF_t, nullptr, WEFFT, HID_, 0, HID_);
    g3_kernel<<<dim3(G4_ / 256), blk, 0, stream>>>(out_b, lstm_Wx, G3v);
    // T1 = enc@out_W[1024:,:] + out_b  (runs after tr_cat frees WEFF_t)
    gemm128<<<dim3(M / 128, (POSE_ + 127) / 128), blk, 0, stream>>>(
        X, out_W + (long)HID_ * POSE_, T1, M, POSE_, DM_, out_b,
        nullptr, nullptr, nullptr, 0);
    dec_init<<<dim3((B_ * HID_ + 255) / 256), blk, 0, stream>>>(vec_h, HP0, CNT);

    // ---- persistent decoder: all 512 steps in one launch ----
    lstm_persist<<<dim3(NBLK_), blk, 0, stream>>>(
        WhT, WEFFT, lstm_Wx, G2, G3v, lstm_b, epoch,
        tgt_seq, dec0, X, vec_c, HP0, HP1, Hall, CNT);

    // ---- final: out = Hall@out_W[:1024] + T1 ----
    gemm128<<<dim3(M / 128, (POSE_ + 127) / 128), blk, 0, stream>>>(
        Hall, out_W, (float*)d_out, M, POSE_, HID_, nullptr, T1,
        nullptr, nullptr, 0);
}

// Round 5
// 34716.385 us; speedup vs baseline: 3.7742x; 3.7742x over previous
//
#include <hip/hip_runtime.h>
#include <math.h>

#define B_ 16
#define S_ 512
#define FRAME_ 438
#define DM_ 800
#define H_ 8
#define DH_ 100
#define FFN_ 1024
#define HID_ 1024
#define POSE_ 274
#define WIN_ 100
#define G4_ 4096     // 4*HID
#define NBLK_ 512    // persistent decoder grid (2 blocks/CU on 256 CUs)
#define KPX_ 320     // padded K for WxT slices (274 -> 320, 10/thread)
#define KPG_ 832     // padded K for G2T slices (800 -> 832, 26/thread)

// ---------------------------------------------------------------------------
// gemm128: fp32, 128x128 tile, 256 thr, 8x8 micro (split 4+4, conflict-free
// LDS). C = A@B (+bias[N]) (+res[M,N]) (+pos_table[posidx[m]]) (relu).
// ---------------------------------------------------------------------------
__global__ __launch_bounds__(256) void gemm128(
    const float* __restrict__ A, const float* __restrict__ Bm,
    float* __restrict__ C, int M, int N, int K,
    const float* __restrict__ bias, const float* __restrict__ res,
    const int* __restrict__ posidx, const float* __restrict__ postab,
    int relu)
{
    __shared__ float As[16 * 132];
    __shared__ float Bs[16 * 132];
    int m0 = blockIdx.x * 128, n0 = blockIdx.y * 128;
    int tid = threadIdx.x;
    int tx = tid & 15, ty = tid >> 4;
    float acc[8][8];
#pragma unroll
    for (int i = 0; i < 8; ++i)
#pragma unroll
        for (int j = 0; j < 8; ++j) acc[i][j] = 0.f;

    for (int k0 = 0; k0 < K; k0 += 16) {
#pragma unroll
        for (int i = 0; i < 8; ++i) {             // A: 128 m x 16 k
            int idx = i * 256 + tid;
            int m = idx >> 4, kl = idx & 15;
            int r = m0 + m, k = k0 + kl;
            As[kl * 132 + m] = (r < M && k < K) ? A[(long)r * K + k] : 0.f;
        }
#pragma unroll
        for (int i = 0; i < 8; ++i) {             // B: 16 k x 128 n
            int idx = i * 256 + tid;
            int n = idx & 127, k = idx >> 7;
            int kk = k0 + k, nn = n0 + n;
            Bs[k * 132 + n] = (kk < K && nn < N) ? Bm[(long)kk * N + nn] : 0.f;
        }
        __syncthreads();
#pragma unroll
        for (int kk = 0; kk < 16; ++kk) {
            float4 a0 = *(const float4*)&As[kk * 132 + ty * 4];
            float4 a1 = *(const float4*)&As[kk * 132 + 64 + ty * 4];
            float4 b0 = *(const float4*)&Bs[kk * 132 + tx * 4];
            float4 b1 = *(const float4*)&Bs[kk * 132 + 64 + tx * 4];
            float a[8] = {a0.x, a0.y, a0.z, a0.w, a1.x, a1.y, a1.z, a1.w};
            float b[8] = {b0.x, b0.y, b0.z, b0.w, b1.x, b1.y, b1.z, b1.w};
#pragma unroll
            for (int i = 0; i < 8; ++i)
#pragma unroll
                for (int j = 0; j < 8; ++j) acc[i][j] += a[i] * b[j];
        }
        __syncthreads();
    }
#pragma unroll
    for (int i = 0; i < 8; ++i) {
        int m = m0 + ((i < 4) ? (ty * 4 + i) : (64 + ty * 4 + i - 4));
        if (m >= M) continue;
#pragma unroll
        for (int j = 0; j < 8; ++j) {
            int n = n0 + ((j < 4) ? (tx * 4 + j) : (64 + tx * 4 + j - 4));
            if (n >= N) continue;
            float v = acc[i][j];
            if (bias) v += bias[n];
            if (res) v += res[(long)m * N + n];
            if (posidx) v += postab[(long)posidx[m] * N + n];
            if (relu) v = fmaxf(v, 0.f);
            C[(long)m * N + n] = v;
        }
    }
}

// ---------------------------------------------------------------------------
// LayerNorm over last dim N (=800), one block per row.
// ---------------------------------------------------------------------------
__global__ __launch_bounds__(256) void ln_f32(
    const float* __restrict__ X, float* __restrict__ Y,
    const float* __restrict__ g, const float* __restrict__ b, int N)
{
    int m = blockIdx.x;
    const float* x = X + (long)m * N;
    __shared__ float red[256];
    int tid = threadIdx.x;
    float s = 0.f;
    for (int i = tid; i < N; i += 256) s += x[i];
    red[tid] = s; __syncthreads();
    for (int o = 128; o > 0; o >>= 1) { if (tid < o) red[tid] += red[tid + o]; __syncthreads(); }
    float mean = red[0] / N;
    __syncthreads();
    float v = 0.f;
    for (int i = tid; i < N; i += 256) { float d = x[i] - mean; v += d * d; }
    red[tid] = v; __syncthreads();
    for (int o = 128; o > 0; o >>= 1) { if (tid < o) red[tid] += red[tid + o]; __syncthreads(); }
    float rs = rsqrtf(red[0] / N + 1e-6f);
    for (int i = tid; i < N; i += 256)
        Y[(long)m * N + i] = (x[i] - mean) * rs * g[i] + b[i];
}

// ---------------------------------------------------------------------------
// Fused banded attention (verified round 1).
// ---------------------------------------------------------------------------
__global__ __launch_bounds__(256) void attn_f32(
    const float* __restrict__ Q, const float* __restrict__ K,
    const float* __restrict__ V, float* __restrict__ O)
{
    int blk = blockIdx.x;
    int qt = blk & 127; int bh = blk >> 7;
    int h = bh & 7; int b = bh >> 3;
    int q0 = qt * 4;
    int tid = threadIdx.x;

    __shared__ float qv[4][DH_];
    __shared__ float sc[4][208];
    __shared__ float red[256];
    __shared__ float inv_den[4];

    for (int i = tid; i < 4 * DH_; i += 256) {
        int qi = i / DH_, d = i - qi * DH_;
        qv[qi][d] = Q[(long)(b * S_ + q0 + qi) * DM_ + h * DH_ + d];
    }
    __syncthreads();

    int w = tid;
    int k = q0 - WIN_ + w;
    bool kvalid = (w < 204) && (k >= 0) && (k < S_);
    float dots[4] = {0.f, 0.f, 0.f, 0.f};
    if (kvalid) {
        const float* krow = K + (long)(b * S_ + k) * DM_ + h * DH_;
        for (int d = 0; d < DH_; ++d) {
            float kvv = krow[d];
#pragma unroll
            for (int qi = 0; qi < 4; ++qi) dots[qi] += qv[qi][d] * kvv;
        }
    }
#pragma unroll
    for (int qi = 0; qi < 4; ++qi) {
        int wq = w - qi;
        if (w < 204 && wq >= 0 && wq < 201)
            sc[qi][wq] = kvalid ? dots[qi] * 0.1f : -1e30f;
    }
    __syncthreads();

    for (int qi = 0; qi < 4; ++qi) {
        float vmax = (tid < 201) ? sc[qi][tid] : -1e30f;
        red[tid] = vmax; __syncthreads();
        for (int o = 128; o > 0; o >>= 1) { if (tid < o) red[tid] = fmaxf(red[tid], red[tid + o]); __syncthreads(); }
        float mx = red[0];
        __syncthreads();
        float e = 0.f;
        if (tid < 201) { e = __expf(sc[qi][tid] - mx); sc[qi][tid] = e; }
        red[tid] = e; __syncthreads();
        for (int o = 128; o > 0; o >>= 1) { if (tid < o) red[tid] += red[tid + o]; __syncthreads(); }
        if (tid == 0) inv_den[qi] = 1.f / red[0];
        __syncthreads();
    }

    if (tid < DH_) {
        int d = tid;
        float o_[4] = {0.f, 0.f, 0.f, 0.f};
        for (int w2 = 0; w2 < 204; ++w2) {
            int k2 = q0 - WIN_ + w2;
            if (k2 < 0 || k2 >= S_) continue;
            float vv = V[(long)(b * S_ + k2) * DM_ + h * DH_ + d];
#pragma unroll
            for (int qi = 0; qi < 4; ++qi) {
                int wq = w2 - qi;
                if (wq >= 0 && wq < 201) o_[qi] += sc[qi][wq] * vv;
            }
        }
#pragma unroll
        for (int qi = 0; qi < 4; ++qi)
            O[(long)(b * S_ + q0 + qi) * DM_ + h * DH_ + d] = o_[qi] * inv_den[qi];
    }
}

// g3[j] = out_b @ Wx
__global__ __launch_bounds__(256) void g3_kernel(
    const float* __restrict__ outb, const float* __restrict__ Wx, float* __restrict__ g3)
{
    int j = blockIdx.x * 256 + threadIdx.x;
    if (j >= G4_) return;
    float s = 0.f;
    for (int p = 0; p < POSE_; ++p) s += outb[p] * Wx[(long)p * G4_ + j];
    g3[j] = s;
}

// ---------------------------------------------------------------------------
// tr_cat: WT[c][k] = (k<K1 ? in1[k][c] : k<K1+K2 ? in2[k-K1][c] : 0)
// in row-major with 4096 cols; WT row stride KP (zero-padded). grid (KP/64,64).
// ---------------------------------------------------------------------------
__global__ __launch_bounds__(256) void tr_cat(
    const float* __restrict__ in1, const float* __restrict__ in2,
    float* __restrict__ WT, int K1, int K2, int KP)
{
    __shared__ float tile[64][65];
    int k0 = blockIdx.x * 64, c0 = blockIdx.y * 64;
    int tid = threadIdx.x;
    int cl = tid & 63, kr = tid >> 6;
#pragma unroll
    for (int i = 0; i < 16; ++i) {
        int kl = i * 4 + kr;
        int k = k0 + kl, c = c0 + cl;
        float v = 0.f;
        if (k < K1) v = in1[(long)k * G4_ + c];
        else if (k < K1 + K2) v = in2[(long)(k - K1) * G4_ + c];
        tile[kl][cl] = v;
    }
    __syncthreads();
    int kl2 = tid & 63, cr = tid >> 6;
#pragma unroll
    for (int i = 0; i < 16; ++i) {
        int ci = i * 4 + cr;
        WT[(long)(c0 + ci) * KP + k0 + kl2] = tile[kl2][ci];
    }
}

// dec_init: HP0 = vec_h; zero barrier area (512 ints).
__global__ __launch_bounds__(256) void dec_init(
    const float* __restrict__ vh, float* __restrict__ HP0, int* __restrict__ BAR)
{
    int i = blockIdx.x * 256 + threadIdx.x;
    if (i < B_ * HID_) HP0[i] = vh[i];
    if (i < 512) BAR[i] = 0;
}

// ---------------------------------------------------------------------------
// lstm_persist v2: one kernel, all 512 steps. 512 blocks x 256 thr,
// 2 blocks/CU (64 KB LDS). Block owns 8 gate-cols (2 hids x 4 gates).
//   - Wh/WEFF slices (32 floats each) live in REGISTERS for all steps.
//   - x-part via pre-transposed WxT/G2T rows (coalesced, L2-hot).
//   - Hierarchical grid barrier: 8 arrival counters (RMW, 128 B apart),
//     block0 aggregates with 8 lanes, release-stores 8 READ-ONLY go-flags;
//     workers poll go with s_sleep(16) (~0.43 us). RMW and polling never
//     share a line (round-4 failure mode).
// BAR layout (ints): cnt g at [g*32], go g at [256 + g*32].
// ---------------------------------------------------------------------------
__global__ __launch_bounds__(256, 2) void lstm_persist(
    const float* __restrict__ WhT, const float* __restrict__ WEFFT,
    const float* __restrict__ WxT, const float* __restrict__ G2T,
    const float* __restrict__ g3, const float* __restrict__ lstm_b,
    const int* __restrict__ epoch,
    const float* __restrict__ tgt, const float* __restrict__ dec0,
    const float* __restrict__ ENC, const float* __restrict__ vec_c,
    float* __restrict__ HPa, float* __restrict__ HPb,
    float* __restrict__ Hall, int* __restrict__ BAR)
{
    __shared__ float lds[16384];   // h panel; reused for partials + gates
    const int tid = threadIdx.x, blk = blockIdx.x;
    const int c = tid & 7, kgr = tid >> 3;
    const int gate = c >> 1, e = c & 1;
    const int col = gate * HID_ + blk * 2 + e;
    const int p = (int)((double)epoch[0] * 0.01);   // match int(epoch*LAMB)
    const int per = p + 10;

    // owner-thread persistent cell state
    const int ob3 = tid >> 1, oe = tid & 1, ohid = blk * 2 + oe;
    float creg = (tid < 32) ? vec_c[ob3 * HID_ + ohid] : 0.f;

    // reducer-thread persistent bias
    float rbias = 0.f, rg3 = 0.f;
    if (tid < 128) {
        int colr = ((tid & 7) >> 1) * HID_ + blk * 2 + (tid & 1);
        rbias = lstm_b[colr];
        rg3 = g3[colr];
    }

    // persistent weight registers (32 + 32 floats)
    float4 wA[8], wB[8];
    {
        const float4* a4 = (const float4*)(WhT   + (long)col * HID_ + kgr * 32);
        const float4* b4 = (const float4*)(WEFFT + (long)col * HID_ + kgr * 32);
#pragma unroll
        for (int j = 0; j < 8; ++j) { wA[j] = a4[j]; wB[j] = b4[j]; }
    }
    const float* wxrow = WxT + (long)col * KPX_ + kgr * 10;
    const float* wgrow = G2T + (long)col * KPG_ + kgr * 26;

    int* cnt = BAR + (blk & 7) * 32;
    int* go  = BAR + 256 + (blk & 7) * 32;

    for (int t = 0; t < S_; ++t) {
        const bool msk = (t % per) >= p;
        const bool useA = msk || (t == 0);
        const float* HIN = (t & 1) ? HPb : HPa;

        // ---- stage h -> lds[b][k], float4 swizzle (j4+kd)&7 (round-4) ----
        {
            const float4* h4 = (const float4*)HIN;
#pragma unroll
            for (int i = 0; i < 16; ++i) {
                int idx = i * 256 + tid;
                int b = idx >> 8, q = idx & 255;
                int kd = q >> 3, j4 = q & 7;
                float4 v = h4[idx];
                *(float4*)&lds[b * 1024 + kd * 32 + ((j4 + kd) & 7) * 4] = v;
            }
        }
        __syncthreads();

        float acc[16];
#pragma unroll
        for (int b = 0; b < 16; ++b) acc[b] = 0.f;

        if (useA) {
            // h-part from registers
#pragma unroll
            for (int j4 = 0; j4 < 8; ++j4) {
                int js = ((j4 + kgr) & 7) * 4;
#pragma unroll
                for (int b = 0; b < 16; ++b) {
                    float4 hv = *(const float4*)&lds[b * 1024 + kgr * 32 + js];
                    acc[b] += wA[j4].x * hv.x + wA[j4].y * hv.y
                            + wA[j4].z * hv.z + wA[j4].w * hv.w;
                }
            }
            // x-part: tgt[t] (mask) or dec0 (t==0), K=274, slice of 10
            const float* xb; long xstr;
            if (msk) { xb = tgt + (long)t * POSE_; xstr = (long)S_ * POSE_; }
            else     { xb = dec0;                  xstr = POSE_; }
            float wx[10];
#pragma unroll
            for (int j = 0; j < 10; ++j) wx[j] = wxrow[j];
#pragma unroll
            for (int j = 0; j < 10; ++j) {
                int kx = kgr * 10 + j;
                if (kx < POSE_) {
                    float wv = wx[j];
#pragma unroll
                    for (int b = 0; b < 16; ++b)
                        acc[b] += wv * xb[(long)b * xstr + kx];
                }
            }
        } else {
            // h-part with folded feedback weights
#pragma unroll
            for (int j4 = 0; j4 < 8; ++j4) {
                int js = ((j4 + kgr) & 7) * 4;
#pragma unroll
                for (int b = 0; b < 16; ++b) {
                    float4 hv = *(const float4*)&lds[b * 1024 + kgr * 32 + js];
                    acc[b] += wB[j4].x * hv.x + wB[j4].y * hv.y
                            + wB[j4].z * hv.z + wB[j4].w * hv.w;
                }
            }
            // enc[t-1]-part, K=800, slice of 26
            const float* xb = ENC + (long)(t - 1) * DM_;
            const long xstr = (long)S_ * DM_;
            float wg[26];
#pragma unroll
            for (int j = 0; j < 26; ++j) wg[j] = wgrow[j];
#pragma unroll
            for (int j = 0; j < 26; ++j) {
                int kx = kgr * 26 + j;
                if (kx < DM_) {
                    float wv = wg[j];
#pragma unroll
                    for (int b = 0; b < 16; ++b)
                        acc[b] += wv * xb[(long)b * xstr + kx];
                }
            }
        }

        // ---- partials -> LDS (h region dead), reduce over 32 k-groups ----
        __syncthreads();
#pragma unroll
        for (int b = 0; b < 16; ++b)
            lds[(kgr * 8 + c) * 17 + b] = acc[b];
        __syncthreads();
        if (tid < 128) {
            int ob = tid >> 3, oc = tid & 7;
            float s = 0.f;
#pragma unroll
            for (int kg = 0; kg < 32; ++kg)
                s += lds[(kg * 8 + oc) * 17 + ob];
            s += rbias;
            if (!useA) s += rg3;
            lds[8192 + oc * 16 + ob] = s;
        }
        __syncthreads();

        // ---- elementwise LSTM update (owner threads) ----
        if (tid < 32) {
            float iv = lds[8192 + (0 * 2 + oe) * 16 + ob3];
            float fv = lds[8192 + (1 * 2 + oe) * 16 + ob3];
            float gv = lds[8192 + (2 * 2 + oe) * 16 + ob3];
            float ov = lds[8192 + (3 * 2 + oe) * 16 + ob3];
            float ig = 1.f / (1.f + __expf(-iv));
            float fg = 1.f / (1.f + __expf(-fv));
            float og = 1.f / (1.f + __expf(-ov));
            float cn = fg * creg + ig * tanhf(gv);
            float hn = og * tanhf(cn);
            creg = cn;
            float* HOUT = (t & 1) ? HPa : HPb;
            HOUT[ob3 * HID_ + ohid] = hn;
            Hall[((long)ob3 * S_ + t) * HID_ + ohid] = hn;
        }
        __syncthreads();   // HOUT writes drained (compiler emits vmcnt(0))

        // ---- hierarchical grid barrier ----
        if (t + 1 < S_) {
            if (tid == 0) {
                __threadfence();
                __hip_atomic_fetch_add(cnt, 1, __ATOMIC_RELEASE,
                                       __HIP_MEMORY_SCOPE_AGENT);
            }
            if (blk == 0) {
                if (tid < 8) {
                    int target = (t + 1) * 64;
                    int guard = 0;
                    while (__hip_atomic_load(BAR + tid * 32, __ATOMIC_ACQUIRE,
                                             __HIP_MEMORY_SCOPE_AGENT) < target
                           && ++guard < (1 << 24))
                        __builtin_amdgcn_s_sleep(8);
                }
                __syncthreads();
                if (tid < 8)
                    __hip_atomic_store(BAR + 256 + tid * 32, t + 1,
                                       __ATOMIC_RELEASE, __HIP_MEMORY_SCOPE_AGENT);
            } else {
                if (tid == 0) {
                    int guard = 0;
                    while (__hip_atomic_load(go, __ATOMIC_ACQUIRE,
                                             __HIP_MEMORY_SCOPE_AGENT) < t + 1
                           && ++guard < (1 << 24))
                        __builtin_amdgcn_s_sleep(16);
                }
                __syncthreads();
            }
        }
    }
}

// ---------------------------------------------------------------------------
extern "C" void kernel_launch(void* const* d_in, const int* in_sizes, int n_in,
                              void* d_out, int out_size, void* d_ws, size_t ws_size,
                              hipStream_t stream) {
    const float* src_seq  = (const float*)d_in[0];
    const int*   src_pos  = (const int*)  d_in[1];
    const float* tgt_seq  = (const float*)d_in[2];
    const float* vec_h    = (const float*)d_in[3];
    const float* vec_c    = (const float*)d_in[4];
    const float* dec0     = (const float*)d_in[5];
    const float* emb_W    = (const float*)d_in[6];
    const float* emb_b    = (const float*)d_in[7];
    const float* pos_tab  = (const float*)d_in[8];
    const float* Wq       = (const float*)d_in[9];
    const float* Wk       = (const float*)d_in[10];
    const float* Wv       = (const float*)d_in[11];
    const float* Wo       = (const float*)d_in[12];
    const float* ln1_g    = (const float*)d_in[13];
    const float* ln1_b    = (const float*)d_in[14];
    const float* ffn_W1   = (const float*)d_in[15];
    const float* ffn_b1   = (const float*)d_in[16];
    const float* ffn_W2   = (const float*)d_in[17];
    const float* ffn_b2   = (const float*)d_in[18];
    const float* ln2_g    = (const float*)d_in[19];
    const float* ln2_b    = (const float*)d_in[20];
    const float* lstm_Wx  = (const float*)d_in[21];
    const float* lstm_Wh  = (const float*)d_in[22];
    const float* lstm_b   = (const float*)d_in[23];
    const float* out_W    = (const float*)d_in[24];
    const float* out_b    = (const float*)d_in[25];
    const int*   epoch    = (const int*)  d_in[26];

    // ---- workspace layout (~165 MB, same proven footprint) ----
    float* ws = (float*)d_ws;
    const long NX = (long)B_ * S_ * DM_;           // 6,553,600
    float* X      = ws;                            // enc (live to the end)
    float* R      = X + NX;                        // 34,603,008-float region
    // encoder phase:
    float* Qb     = R;
    float* Kb     = Qb + NX;
    float* Vb     = Kb + NX;
    float* Ob     = Vb + NX;
    float* FFNH   = Ob + NX;
    // decoder phase (aliases into R):
    float* WEFF_t = R;                             // 4,194,304 (dead after tr_cat)
    float* WhT    = R + 4194304;                   // 4,194,304 (4096 x 1024)
    float* WEFFT  = R + 8388608;                   // 4,194,304 (4096 x 1024)
    float* G2     = R + 12582912;                  // 3,276,800 (800 x 4096)
    float* Hall   = R + 15859712;                  // 8,388,608 (B*S x 1024)
    float* T1     = R + 24248320;                  // 2,244,608 (B*S x 274)
    float* WxT    = R + 26492928;                  // 1,310,720 (4096 x 320)
    float* G2T    = R + 27803648;                  // 3,407,872 (4096 x 832)
    float* TAIL   = R + 34603008;
    float* G3v    = TAIL;                          // 4096
    float* HP0    = G3v + G4_;                     // 16384
    float* HP1    = HP0 + B_ * HID_;               // 16384
    int*   BAR    = (int*)(HP1 + B_ * HID_);       // 512 ints

    const int M = B_ * S_; // 8192
    dim3 blk(256);

    // ---- encoder ----
    gemm128<<<dim3(M / 128, (DM_ + 127) / 128), blk, 0, stream>>>(
        src_seq, emb_W, X, M, DM_, FRAME_, emb_b, nullptr, src_pos, pos_tab, 0);
    gemm128<<<dim3(M / 128, (DM_ + 127) / 128), blk, 0, stream>>>(
        X, Wq, Qb, M, DM_, DM_, nullptr, nullptr, nullptr, nullptr, 0);
    gemm128<<<dim3(M / 128, (DM_ + 127) / 128), blk, 0, stream>>>(
        X, Wk, Kb, M, DM_, DM_, nullptr, nullptr, nullptr, nullptr, 0);
    gemm128<<<dim3(M / 128, (DM_ + 127) / 128), blk, 0, stream>>>(
        X, Wv, Vb, M, DM_, DM_, nullptr, nullptr, nullptr, nullptr, 0);
    attn_f32<<<dim3(B_ * H_ * (S_ / 4)), blk, 0, stream>>>(Qb, Kb, Vb, Ob);
    gemm128<<<dim3(M / 128, (DM_ + 127) / 128), blk, 0, stream>>>(
        Ob, Wo, FFNH, M, DM_, DM_, nullptr, X, nullptr, nullptr, 0);
    ln_f32<<<dim3(M), blk, 0, stream>>>(FFNH, X, ln1_g, ln1_b, DM_);
    gemm128<<<dim3(M / 128, FFN_ / 128), blk, 0, stream>>>(
        X, ffn_W1, FFNH, M, FFN_, DM_, ffn_b1, nullptr, nullptr, nullptr, 1);
    gemm128<<<dim3(M / 128, (DM_ + 127) / 128), blk, 0, stream>>>(
        FFNH, ffn_W2, Ob, M, DM_, FFN_, ffn_b2, X, nullptr, nullptr, 0);
    ln_f32<<<dim3(M), blk, 0, stream>>>(Ob, X, ln2_g, ln2_b, DM_);   // X = enc

    // ---- decoder precompute ----
    // WEFF_t = out_W[:1024]@lstm_Wx + lstm_Wh   (1024 x 4096)
    gemm128<<<dim3(HID_ / 128, G4_ / 128), blk, 0, stream>>>(
        out_W, lstm_Wx, WEFF_t, HID_, G4_, POSE_, nullptr, lstm_Wh,
        nullptr, nullptr, 0);
    // G2 = out_W[1024:]@lstm_Wx   (800 x 4096)
    gemm128<<<dim3((DM_ + 127) / 128, G4_ / 128), blk, 0, stream>>>(
        out_W + (long)HID_ * POSE_, lstm_Wx, G2, DM_, G4_, POSE_,
        nullptr, nullptr, nullptr, nullptr, 0);
    // transposed step weights
    tr_cat<<<dim3(HID_ / 64, G4_ / 64), blk, 0, stream>>>(
        lstm_Wh, nullptr, WhT, HID_, 0, HID_);
    tr_cat<<<dim3(HID_ / 64, G4_ / 64), blk, 0, stream>>>(
        WEFF_t, nullptr, WEFFT, HID_, 0, HID_);
    tr_cat<<<dim3(KPX_ / 64, G4_ / 64), blk, 0, stream>>>(
        lstm_Wx, nullptr, WxT, POSE_, 0, KPX_);
    tr_cat<<<dim3(KPG_ / 64, G4_ / 64), blk, 0, stream>>>(
        G2, nullptr, G2T, DM_, 0, KPG_);
    g3_kernel<<<dim3(G4_ / 256), blk, 0, stream>>>(out_b, lstm_Wx, G3v);
    // T1 = enc@out_W[1024:,:] + out_b  (after tr_cat frees WEFF_t)
    gemm128<<<dim3(M / 128, (POSE_ + 127) / 128), blk, 0, stream>>>(
        X, out_W + (long)HID_ * POSE_, T1, M, POSE_, DM_, out_b,
        nullptr, nullptr, nullptr, 0);
    dec_init<<<dim3((B_ * HID_ + 255) / 256), blk, 0, stream>>>(vec_h, HP0, BAR);

    // ---- persistent decoder: all 512 steps in one launch ----
    lstm_persist<<<dim3(NBLK_), blk, 0, stream>>>(
        WhT, WEFFT, WxT, G2T, G3v, lstm_b, epoch,
        tgt_seq, dec0, X, vec_c, HP0, HP1, Hall, BAR);

    // ---- final: out = Hall@out_W[:1024] + T1 ----
    gemm128<<<dim3(M / 128, (POSE_ + 127) / 128), blk, 0, stream>>>(
        Hall, out_W, (float*)d_out, M, POSE_, HID_, nullptr, T1,
        nullptr, nullptr, 0);
}

// Round 7
// 24299.867 us; speedup vs baseline: 5.3921x; 1.4287x over previous
//
#include <hip/hip_runtime.h>
#include <math.h>

#define B_ 16
#define S_ 512
#define FRAME_ 438
#define DM_ 800
#define H_ 8
#define DH_ 100
#define FFN_ 1024
#define HID_ 1024
#define POSE_ 274
#define WIN_ 100
#define G4_ 4096     // 4*HID
#define NBLK_ 512    // persistent decoder grid (2 blocks/CU on 256 CUs)
#define KPX_ 320     // padded K for WxT slices (274 -> 320, 10/thread)
#define KPG_ 832     // padded K for G2T slices (800 -> 832, 26/thread)

// ---------------------------------------------------------------------------
// gemm128: fp32, 128x128 tile, 256 thr, 8x8 micro (split 4+4, conflict-free
// LDS). C = A@B (+bias[N]) (+res[M,N]) (+pos_table[posidx[m]]) (relu).
// ---------------------------------------------------------------------------
__global__ __launch_bounds__(256) void gemm128(
    const float* __restrict__ A, const float* __restrict__ Bm,
    float* __restrict__ C, int M, int N, int K,
    const float* __restrict__ bias, const float* __restrict__ res,
    const int* __restrict__ posidx, const float* __restrict__ postab,
    int relu)
{
    __shared__ float As[16 * 132];
    __shared__ float Bs[16 * 132];
    int m0 = blockIdx.x * 128, n0 = blockIdx.y * 128;
    int tid = threadIdx.x;
    int tx = tid & 15, ty = tid >> 4;
    float acc[8][8];
#pragma unroll
    for (int i = 0; i < 8; ++i)
#pragma unroll
        for (int j = 0; j < 8; ++j) acc[i][j] = 0.f;

    for (int k0 = 0; k0 < K; k0 += 16) {
#pragma unroll
        for (int i = 0; i < 8; ++i) {             // A: 128 m x 16 k
            int idx = i * 256 + tid;
            int m = idx >> 4, kl = idx & 15;
            int r = m0 + m, k = k0 + kl;
            As[kl * 132 + m] = (r < M && k < K) ? A[(long)r * K + k] : 0.f;
        }
#pragma unroll
        for (int i = 0; i < 8; ++i) {             // B: 16 k x 128 n
            int idx = i * 256 + tid;
            int n = idx & 127, k = idx >> 7;
            int kk = k0 + k, nn = n0 + n;
            Bs[k * 132 + n] = (kk < K && nn < N) ? Bm[(long)kk * N + nn] : 0.f;
        }
        __syncthreads();
#pragma unroll
        for (int kk = 0; kk < 16; ++kk) {
            float4 a0 = *(const float4*)&As[kk * 132 + ty * 4];
            float4 a1 = *(const float4*)&As[kk * 132 + 64 + ty * 4];
            float4 b0 = *(const float4*)&Bs[kk * 132 + tx * 4];
            float4 b1 = *(const float4*)&Bs[kk * 132 + 64 + tx * 4];
            float a[8] = {a0.x, a0.y, a0.z, a0.w, a1.x, a1.y, a1.z, a1.w};
            float b[8] = {b0.x, b0.y, b0.z, b0.w, b1.x, b1.y, b1.z, b1.w};
#pragma unroll
            for (int i = 0; i < 8; ++i)
#pragma unroll
                for (int j = 0; j < 8; ++j) acc[i][j] += a[i] * b[j];
        }
        __syncthreads();
    }
#pragma unroll
    for (int i = 0; i < 8; ++i) {
        int m = m0 + ((i < 4) ? (ty * 4 + i) : (64 + ty * 4 + i - 4));
        if (m >= M) continue;
#pragma unroll
        for (int j = 0; j < 8; ++j) {
            int n = n0 + ((j < 4) ? (tx * 4 + j) : (64 + tx * 4 + j - 4));
            if (n >= N) continue;
            float v = acc[i][j];
            if (bias) v += bias[n];
            if (res) v += res[(long)m * N + n];
            if (posidx) v += postab[(long)posidx[m] * N + n];
            if (relu) v = fmaxf(v, 0.f);
            C[(long)m * N + n] = v;
        }
    }
}

// ---------------------------------------------------------------------------
// LayerNorm over last dim N (=800), one block per row.
// ---------------------------------------------------------------------------
__global__ __launch_bounds__(256) void ln_f32(
    const float* __restrict__ X, float* __restrict__ Y,
    const float* __restrict__ g, const float* __restrict__ b, int N)
{
    int m = blockIdx.x;
    const float* x = X + (long)m * N;
    __shared__ float red[256];
    int tid = threadIdx.x;
    float s = 0.f;
    for (int i = tid; i < N; i += 256) s += x[i];
    red[tid] = s; __syncthreads();
    for (int o = 128; o > 0; o >>= 1) { if (tid < o) red[tid] += red[tid + o]; __syncthreads(); }
    float mean = red[0] / N;
    __syncthreads();
    float v = 0.f;
    for (int i = tid; i < N; i += 256) { float d = x[i] - mean; v += d * d; }
    red[tid] = v; __syncthreads();
    for (int o = 128; o > 0; o >>= 1) { if (tid < o) red[tid] += red[tid + o]; __syncthreads(); }
    float rs = rsqrtf(red[0] / N + 1e-6f);
    for (int i = tid; i < N; i += 256)
        Y[(long)m * N + i] = (x[i] - mean) * rs * g[i] + b[i];
}

// ---------------------------------------------------------------------------
// Fused banded attention (verified round 1).
// ---------------------------------------------------------------------------
__global__ __launch_bounds__(256) void attn_f32(
    const float* __restrict__ Q, const float* __restrict__ K,
    const float* __restrict__ V, float* __restrict__ O)
{
    int blk = blockIdx.x;
    int qt = blk & 127; int bh = blk >> 7;
    int h = bh & 7; int b = bh >> 3;
    int q0 = qt * 4;
    int tid = threadIdx.x;

    __shared__ float qv[4][DH_];
    __shared__ float sc[4][208];
    __shared__ float red[256];
    __shared__ float inv_den[4];

    for (int i = tid; i < 4 * DH_; i += 256) {
        int qi = i / DH_, d = i - qi * DH_;
        qv[qi][d] = Q[(long)(b * S_ + q0 + qi) * DM_ + h * DH_ + d];
    }
    __syncthreads();

    int w = tid;
    int k = q0 - WIN_ + w;
    bool kvalid = (w < 204) && (k >= 0) && (k < S_);
    float dots[4] = {0.f, 0.f, 0.f, 0.f};
    if (kvalid) {
        const float* krow = K + (long)(b * S_ + k) * DM_ + h * DH_;
        for (int d = 0; d < DH_; ++d) {
            float kvv = krow[d];
#pragma unroll
            for (int qi = 0; qi < 4; ++qi) dots[qi] += qv[qi][d] * kvv;
        }
    }
#pragma unroll
    for (int qi = 0; qi < 4; ++qi) {
        int wq = w - qi;
        if (w < 204 && wq >= 0 && wq < 201)
            sc[qi][wq] = kvalid ? dots[qi] * 0.1f : -1e30f;
    }
    __syncthreads();

    for (int qi = 0; qi < 4; ++qi) {
        float vmax = (tid < 201) ? sc[qi][tid] : -1e30f;
        red[tid] = vmax; __syncthreads();
        for (int o = 128; o > 0; o >>= 1) { if (tid < o) red[tid] = fmaxf(red[tid], red[tid + o]); __syncthreads(); }
        float mx = red[0];
        __syncthreads();
        float e = 0.f;
        if (tid < 201) { e = __expf(sc[qi][tid] - mx); sc[qi][tid] = e; }
        red[tid] = e; __syncthreads();
        for (int o = 128; o > 0; o >>= 1) { if (tid < o) red[tid] += red[tid + o]; __syncthreads(); }
        if (tid == 0) inv_den[qi] = 1.f / red[0];
        __syncthreads();
    }

    if (tid < DH_) {
        int d = tid;
        float o_[4] = {0.f, 0.f, 0.f, 0.f};
        for (int w2 = 0; w2 < 204; ++w2) {
            int k2 = q0 - WIN_ + w2;
            if (k2 < 0 || k2 >= S_) continue;
            float vv = V[(long)(b * S_ + k2) * DM_ + h * DH_ + d];
#pragma unroll
            for (int qi = 0; qi < 4; ++qi) {
                int wq = w2 - qi;
                if (wq >= 0 && wq < 201) o_[qi] += sc[qi][wq] * vv;
            }
        }
#pragma unroll
        for (int qi = 0; qi < 4; ++qi)
            O[(long)(b * S_ + q0 + qi) * DM_ + h * DH_ + d] = o_[qi] * inv_den[qi];
    }
}

// g3[j] = out_b @ Wx
__global__ __launch_bounds__(256) void g3_kernel(
    const float* __restrict__ outb, const float* __restrict__ Wx, float* __restrict__ g3)
{
    int j = blockIdx.x * 256 + threadIdx.x;
    if (j >= G4_) return;
    float s = 0.f;
    for (int p = 0; p < POSE_; ++p) s += outb[p] * Wx[(long)p * G4_ + j];
    g3[j] = s;
}

// ---------------------------------------------------------------------------
// tr_cat: WT[c][k] = (k<K1 ? in1[k][c] : 0), zero-padded to KP.
// ---------------------------------------------------------------------------
__global__ __launch_bounds__(256) void tr_cat(
    const float* __restrict__ in1, const float* __restrict__ in2,
    float* __restrict__ WT, int K1, int K2, int KP)
{
    __shared__ float tile[64][65];
    int k0 = blockIdx.x * 64, c0 = blockIdx.y * 64;
    int tid = threadIdx.x;
    int cl = tid & 63, kr = tid >> 6;
#pragma unroll
    for (int i = 0; i < 16; ++i) {
        int kl = i * 4 + kr;
        int k = k0 + kl, c = c0 + cl;
        float v = 0.f;
        if (k < K1) v = in1[(long)k * G4_ + c];
        else if (k < K1 + K2) v = in2[(long)(k - K1) * G4_ + c];
        tile[kl][cl] = v;
    }
    __syncthreads();
    int kl2 = tid & 63, cr = tid >> 6;
#pragma unroll
    for (int i = 0; i < 16; ++i) {
        int ci = i * 4 + cr;
        WT[(long)(c0 + ci) * KP + k0 + kl2] = tile[kl2][ci];
    }
}

// dec_init: HP0 = vec_h (agent-scope stores); zero barrier area.
__global__ __launch_bounds__(256) void dec_init(
    const float* __restrict__ vh, float* __restrict__ HP0, int* __restrict__ BAR)
{
    int i = blockIdx.x * 256 + threadIdx.x;
    if (i < B_ * HID_)
        __hip_atomic_store(&HP0[i], vh[i], __ATOMIC_RELAXED,
                           __HIP_MEMORY_SCOPE_AGENT);
    if (i < 4096) BAR[i] = 0;
}

// ---------------------------------------------------------------------------
// lstm_persist v4: one kernel, all 512 steps. 512 blocks x 256 thr,
// 2 blocks/CU. ALL atomics RELAXED (no acquire/release -> no cache
// maintenance storms). Ordering by construction: __syncthreads() drains
// vmcnt(0) for every wave, so relaxed agent-scope h stores are at the MALL
// (single coherence point) before the arrival add. h re-read each step via
// relaxed agent-scope ATOMIC loads (coherent, pipelined, no invalidation).
// Barrier: 64 arrival lines (8 blocks each) -> block0 64-lane ballot poll
// -> 64 go lines (<=8 pollers each).
// BAR layout (ints): cnt line g at [g*32]; go line g at [2048 + g*32].
// ---------------------------------------------------------------------------
__global__ __launch_bounds__(256, 2) void lstm_persist(
    const float* __restrict__ WhT, const float* __restrict__ WEFFT,
    const float* __restrict__ WxT, const float* __restrict__ G2T,
    const float* __restrict__ g3, const float* __restrict__ lstm_b,
    const int* __restrict__ epoch,
    const float* __restrict__ tgt, const float* __restrict__ dec0,
    const float* __restrict__ ENC, const float* __restrict__ vec_c,
    float* __restrict__ HPa, float* __restrict__ HPb,
    float* __restrict__ Hall, int* __restrict__ BAR)
{
    __shared__ float lds[16384];   // h panel; reused for partials + gates
    const int tid = threadIdx.x, blk = blockIdx.x;
    const int c = tid & 7, kgr = tid >> 3;
    const int gate = c >> 1, e = c & 1;
    const int col = gate * HID_ + blk * 2 + e;
    const int p = (int)((double)epoch[0] * 0.01);   // match int(epoch*LAMB)
    const int per = p + 10;

    // owner-thread persistent cell state
    const int ob3 = tid >> 1, oe = tid & 1, ohid = blk * 2 + oe;
    float creg = (tid < 32) ? vec_c[ob3 * HID_ + ohid] : 0.f;

    // reducer-thread persistent bias
    float rbias = 0.f, rg3 = 0.f;
    if (tid < 128) {
        int colr = ((tid & 7) >> 1) * HID_ + blk * 2 + (tid & 1);
        rbias = lstm_b[colr];
        rg3 = g3[colr];
    }

    // persistent weight registers (32 + 32 floats)
    float4 wA[8], wB[8];
    {
        const float4* a4 = (const float4*)(WhT   + (long)col * HID_ + kgr * 32);
        const float4* b4 = (const float4*)(WEFFT + (long)col * HID_ + kgr * 32);
#pragma unroll
        for (int j = 0; j < 8; ++j) { wA[j] = a4[j]; wB[j] = b4[j]; }
    }
    const float* wxrow = WxT + (long)col * KPX_ + kgr * 10;
    const float* wgrow = G2T + (long)col * KPG_ + kgr * 26;

    for (int t = 0; t < S_; ++t) {
        const bool msk = (t % per) >= p;
        const bool useA = msk || (t == 0);
        const float* HIN = (t & 1) ? HPb : HPa;

        // ---- stage h: 64 coherent scalar loads (relaxed agent atomics,
        //      pipelined by compiler) -> swizzled LDS ((j4+kd)&7 rotation) ----
        {
            float hv[64];
#pragma unroll
            for (int i = 0; i < 64; ++i)
                hv[i] = __hip_atomic_load(&HIN[i * 256 + tid],
                                          __ATOMIC_RELAXED,
                                          __HIP_MEMORY_SCOPE_AGENT);
#pragma unroll
            for (int i = 0; i < 64; ++i) {
                int fi = i * 256 + tid;
                int b = fi >> 10, k = fi & 1023;
                int kd = k >> 5, j4 = (k >> 2) & 7, l = k & 3;
                lds[b * 1024 + kd * 32 + ((j4 + kd) & 7) * 4 + l] = hv[i];
            }
        }
        __syncthreads();

        float acc[16];
#pragma unroll
        for (int b = 0; b < 16; ++b) acc[b] = 0.f;

        if (useA) {
#pragma unroll
            for (int j4 = 0; j4 < 8; ++j4) {
                int js = ((j4 + kgr) & 7) * 4;
#pragma unroll
                for (int b = 0; b < 16; ++b) {
                    float4 hv = *(const float4*)&lds[b * 1024 + kgr * 32 + js];
                    acc[b] += wA[j4].x * hv.x + wA[j4].y * hv.y
                            + wA[j4].z * hv.z + wA[j4].w * hv.w;
                }
            }
            const float* xb; long xstr;
            if (msk) { xb = tgt + (long)t * POSE_; xstr = (long)S_ * POSE_; }
            else     { xb = dec0;                  xstr = POSE_; }
            float wx[10];
#pragma unroll
            for (int j = 0; j < 10; ++j) wx[j] = wxrow[j];
#pragma unroll
            for (int j = 0; j < 10; ++j) {
                int kx = kgr * 10 + j;
                if (kx < POSE_) {
                    float wv = wx[j];
#pragma unroll
                    for (int b = 0; b < 16; ++b)
                        acc[b] += wv * xb[(long)b * xstr + kx];
                }
            }
        } else {
#pragma unroll
            for (int j4 = 0; j4 < 8; ++j4) {
                int js = ((j4 + kgr) & 7) * 4;
#pragma unroll
                for (int b = 0; b < 16; ++b) {
                    float4 hv = *(const float4*)&lds[b * 1024 + kgr * 32 + js];
                    acc[b] += wB[j4].x * hv.x + wB[j4].y * hv.y
                            + wB[j4].z * hv.z + wB[j4].w * hv.w;
                }
            }
            const float* xb = ENC + (long)(t - 1) * DM_;
            const long xstr = (long)S_ * DM_;
            float wg[26];
#pragma unroll
            for (int j = 0; j < 26; ++j) wg[j] = wgrow[j];
#pragma unroll
            for (int j = 0; j < 26; ++j) {
                int kx = kgr * 26 + j;
                if (kx < DM_) {
                    float wv = wg[j];
#pragma unroll
                    for (int b = 0; b < 16; ++b)
                        acc[b] += wv * xb[(long)b * xstr + kx];
                }
            }
        }

        // ---- partials -> LDS (h region dead), reduce over 32 k-groups ----
        __syncthreads();
#pragma unroll
        for (int b = 0; b < 16; ++b)
            lds[(kgr * 8 + c) * 17 + b] = acc[b];
        __syncthreads();
        if (tid < 128) {
            int ob = tid >> 3, oc = tid & 7;
            float s = 0.f;
#pragma unroll
            for (int kg = 0; kg < 32; ++kg)
                s += lds[(kg * 8 + oc) * 17 + ob];
            s += rbias;
            if (!useA) s += rg3;
            lds[8192 + oc * 16 + ob] = s;
        }
        __syncthreads();

        // ---- elementwise LSTM update; h out via agent-scope stores ----
        if (tid < 32) {
            float iv = lds[8192 + (0 * 2 + oe) * 16 + ob3];
            float fv = lds[8192 + (1 * 2 + oe) * 16 + ob3];
            float gv = lds[8192 + (2 * 2 + oe) * 16 + ob3];
            float ov = lds[8192 + (3 * 2 + oe) * 16 + ob3];
            float ig = 1.f / (1.f + __expf(-iv));
            float fg = 1.f / (1.f + __expf(-fv));
            float og = 1.f / (1.f + __expf(-ov));
            float cn = fg * creg + ig * tanhf(gv);
            float hn = og * tanhf(cn);
            creg = cn;
            float* HOUT = (t & 1) ? HPa : HPb;
            __hip_atomic_store(&HOUT[ob3 * HID_ + ohid], hn, __ATOMIC_RELAXED,
                               __HIP_MEMORY_SCOPE_AGENT);
            Hall[((long)ob3 * S_ + t) * HID_ + ohid] = hn;
        }
        __syncthreads();   // drains vmcnt(0) for ALL waves -> h at MALL

        // ---- grid barrier: relaxed-only, 64 arrival + 64 go lines ----
        if (t + 1 < S_) {
            if (tid == 0)
                __hip_atomic_fetch_add(BAR + (blk & 63) * 32, 1,
                                       __ATOMIC_RELAXED, __HIP_MEMORY_SCOPE_AGENT);
            if (blk == 0) {
                if (tid < 64) {
                    int target = (t + 1) * 8;
                    int guard = 0;
                    while (++guard < (1 << 24)) {
                        int v = __hip_atomic_load(BAR + tid * 32,
                                                  __ATOMIC_RELAXED,
                                                  __HIP_MEMORY_SCOPE_AGENT);
                        if (__ballot(v >= target) == ~0ull) break;
                        __builtin_amdgcn_s_sleep(2);
                    }
                }
                __syncthreads();
                if (tid < 64)
                    __hip_atomic_store(BAR + 2048 + tid * 32, t + 1,
                                       __ATOMIC_RELAXED, __HIP_MEMORY_SCOPE_AGENT);
            } else {
                if (tid == 0) {
                    int guard = 0;
                    while (__hip_atomic_load(BAR + 2048 + (blk & 63) * 32,
                                             __ATOMIC_RELAXED,
                                             __HIP_MEMORY_SCOPE_AGENT) < t + 1
                           && ++guard < (1 << 24))
                        __builtin_amdgcn_s_sleep(2);
                }
                __syncthreads();
            }
        }
    }
}

// ---------------------------------------------------------------------------
extern "C" void kernel_launch(void* const* d_in, const int* in_sizes, int n_in,
                              void* d_out, int out_size, void* d_ws, size_t ws_size,
                              hipStream_t stream) {
    const float* src_seq  = (const float*)d_in[0];
    const int*   src_pos  = (const int*)  d_in[1];
    const float* tgt_seq  = (const float*)d_in[2];
    const float* vec_h    = (const float*)d_in[3];
    const float* vec_c    = (const float*)d_in[4];
    const float* dec0     = (const float*)d_in[5];
    const float* emb_W    = (const float*)d_in[6];
    const float* emb_b    = (const float*)d_in[7];
    const float* pos_tab  = (const float*)d_in[8];
    const float* Wq       = (const float*)d_in[9];
    const float* Wk       = (const float*)d_in[10];
    const float* Wv       = (const float*)d_in[11];
    const float* Wo       = (const float*)d_in[12];
    const float* ln1_g    = (const float*)d_in[13];
    const float* ln1_b    = (const float*)d_in[14];
    const float* ffn_W1   = (const float*)d_in[15];
    const float* ffn_b1   = (const float*)d_in[16];
    const float* ffn_W2   = (const float*)d_in[17];
    const float* ffn_b2   = (const float*)d_in[18];
    const float* ln2_g    = (const float*)d_in[19];
    const float* ln2_b    = (const float*)d_in[20];
    const float* lstm_Wx  = (const float*)d_in[21];
    const float* lstm_Wh  = (const float*)d_in[22];
    const float* lstm_b   = (const float*)d_in[23];
    const float* out_W    = (const float*)d_in[24];
    const float* out_b    = (const float*)d_in[25];
    const int*   epoch    = (const int*)  d_in[26];

    // ---- workspace layout (~165 MB, proven footprint) ----
    float* ws = (float*)d_ws;
    const long NX = (long)B_ * S_ * DM_;           // 6,553,600
    float* X      = ws;                            // enc (live to the end)
    float* R      = X + NX;                        // 34,603,008-float region
    // encoder phase:
    float* Qb     = R;
    float* Kb     = Qb + NX;
    float* Vb     = Kb + NX;
    float* Ob     = Vb + NX;
    float* FFNH   = Ob + NX;
    // decoder phase (aliases into R):
    float* WEFF_t = R;                             // 4,194,304 (dead after tr_cat)
    float* WhT    = R + 4194304;                   // 4,194,304 (4096 x 1024)
    float* WEFFT  = R + 8388608;                   // 4,194,304 (4096 x 1024)
    float* G2     = R + 12582912;                  // 3,276,800 (800 x 4096)
    float* Hall   = R + 15859712;                  // 8,388,608 (B*S x 1024)
    float* T1     = R + 24248320;                  // 2,244,608 (B*S x 274)
    float* WxT    = R + 26492928;                  // 1,310,720 (4096 x 320)
    float* G2T    = R + 27803648;                  // 3,407,872 (4096 x 832)
    float* TAIL   = R + 34603008;
    float* G3v    = TAIL;                          // 4096
    float* HP0    = G3v + G4_;                     // 16384
    float* HP1    = HP0 + B_ * HID_;               // 16384
    int*   BAR    = (int*)(HP1 + B_ * HID_);       // 4096 ints

    const int M = B_ * S_; // 8192
    dim3 blk(256);

    // ---- encoder ----
    gemm128<<<dim3(M / 128, (DM_ + 127) / 128), blk, 0, stream>>>(
        src_seq, emb_W, X, M, DM_, FRAME_, emb_b, nullptr, src_pos, pos_tab, 0);
    gemm128<<<dim3(M / 128, (DM_ + 127) / 128), blk, 0, stream>>>(
        X, Wq, Qb, M, DM_, DM_, nullptr, nullptr, nullptr, nullptr, 0);
    gemm128<<<dim3(M / 128, (DM_ + 127) / 128), blk, 0, stream>>>(
        X, Wk, Kb, M, DM_, DM_, nullptr, nullptr, nullptr, nullptr, 0);
    gemm128<<<dim3(M / 128, (DM_ + 127) / 128), blk, 0, stream>>>(
        X, Wv, Vb, M, DM_, DM_, nullptr, nullptr, nullptr, nullptr, 0);
    attn_f32<<<dim3(B_ * H_ * (S_ / 4)), blk, 0, stream>>>(Qb, Kb, Vb, Ob);
    gemm128<<<dim3(M / 128, (DM_ + 127) / 128), blk, 0, stream>>>(
        Ob, Wo, FFNH, M, DM_, DM_, nullptr, X, nullptr, nullptr, 0);
    ln_f32<<<dim3(M), blk, 0, stream>>>(FFNH, X, ln1_g, ln1_b, DM_);
    gemm128<<<dim3(M / 128, FFN_ / 128), blk, 0, stream>>>(
        X, ffn_W1, FFNH, M, FFN_, DM_, ffn_b1, nullptr, nullptr, nullptr, 1);
    gemm128<<<dim3(M / 128, (DM_ + 127) / 128), blk, 0, stream>>>(
        FFNH, ffn_W2, Ob, M, DM_, FFN_, ffn_b2, X, nullptr, nullptr, 0);
    ln_f32<<<dim3(M), blk, 0, stream>>>(Ob, X, ln2_g, ln2_b, DM_);   // X = enc

    // ---- decoder precompute ----
    gemm128<<<dim3(HID_ / 128, G4_ / 128), blk, 0, stream>>>(
        out_W, lstm_Wx, WEFF_t, HID_, G4_, POSE_, nullptr, lstm_Wh,
        nullptr, nullptr, 0);
    gemm128<<<dim3((DM_ + 127) / 128, G4_ / 128), blk, 0, stream>>>(
        out_W + (long)HID_ * POSE_, lstm_Wx, G2, DM_, G4_, POSE_,
        nullptr, nullptr, nullptr, nullptr, 0);
    tr_cat<<<dim3(HID_ / 64, G4_ / 64), blk, 0, stream>>>(
        lstm_Wh, nullptr, WhT, HID_, 0, HID_);
    tr_cat<<<dim3(HID_ / 64, G4_ / 64), blk, 0, stream>>>(
        WEFF_t, nullptr, WEFFT, HID_, 0, HID_);
    tr_cat<<<dim3(KPX_ / 64, G4_ / 64), blk, 0, stream>>>(
        lstm_Wx, nullptr, WxT, POSE_, 0, KPX_);
    tr_cat<<<dim3(KPG_ / 64, G4_ / 64), blk, 0, stream>>>(
        G2, nullptr, G2T, DM_, 0, KPG_);
    g3_kernel<<<dim3(G4_ / 256), blk, 0, stream>>>(out_b, lstm_Wx, G3v);
    gemm128<<<dim3(M / 128, (POSE_ + 127) / 128), blk, 0, stream>>>(
        X, out_W + (long)HID_ * POSE_, T1, M, POSE_, DM_, out_b,
        nullptr, nullptr, nullptr, 0);
    dec_init<<<dim3((B_ * HID_ + 255) / 256), blk, 0, stream>>>(vec_h, HP0, BAR);

    // ---- persistent decoder: all 512 steps in one launch ----
    lstm_persist<<<dim3(NBLK_), blk, 0, stream>>>(
        WhT, WEFFT, WxT, G2T, G3v, lstm_b, epoch,
        tgt_seq, dec0, X, vec_c, HP0, HP1, Hall, BAR);

    // ---- final: out = Hall@out_W[:1024] + T1 ----
    gemm128<<<dim3(M / 128, (POSE_ + 127) / 128), blk, 0, stream>>>(
        Hall, out_W, (float*)d_out, M, POSE_, HID_, nullptr, T1,
        nullptr, nullptr, 0);
}